// Round 2
// baseline (244.950 us; speedup 1.0000x reference)
//
#include <hip/hip_runtime.h>
#include <hip/hip_bf16.h>

// Problem constants (fixed by reference):
//   B=16, L=512, D=C=F=256, K=3, M=2048, EPS=1e-5
// All float tensors are float32 (reference dtype); target is int32.
#define Bn 16
#define Ln 512
#define Cn 256
#define Fn 256
#define Kn 3
#define Mn 2048
#define RROWS 16

// ---------- weight transpose: w (F,C,K) f32 -> wT (K,C,F) f32 ----------
__global__ void transpose_w(const float* __restrict__ w,
                            float* __restrict__ wT) {
    int idx = blockIdx.x * 256 + threadIdx.x;   // over F*C*K = 196608
    if (idx >= Fn * Cn * Kn) return;
    int k = idx % 3;
    int d = (idx / 3) & 255;
    int f = idx / (3 * Cn);
    wT[(k * Cn + d) * Fn + f] = w[idx];
}

// ---------- fused conv1d(K=3,SAME) + bias + LayerNorm + ReLU ----------
// One block = 16 output rows (l0..l0+15) of one batch. 256 threads:
// compute phase: thread f computes out[f] for all 16 rows (f32 accum).
// LN phase: wave w handles rows 4w..4w+3, shuffle-reduce over F.
__global__ __launch_bounds__(256) void conv_ln_relu(
    const float* __restrict__ in,    // (B,L,C) f32
    const float* __restrict__ wT,    // (K,C,F) f32
    const float* __restrict__ bias,  // (F)
    const float* __restrict__ gamma, // (F)
    const float* __restrict__ beta,  // (F)
    float* __restrict__ out)         // (B,L,F) f32
{
    __shared__ float xs[RROWS + 2][Cn];   // 18*256*4 = 18432 B input slab
    __shared__ float hs[RROWS][Cn];       // 16384 B conv result for LN

    const int t = threadIdx.x;
    const int blocksPerB = Ln / RROWS;    // 32
    const int b  = blockIdx.x / blocksPerB;
    const int l0 = (blockIdx.x % blocksPerB) * RROWS;

    // load input slab rows l0-1 .. l0+16, zero-padded at edges (float4)
    for (int idx = t; idx < (RROWS + 2) * (Cn / 4); idx += 256) {
        int row = idx >> 6;           // Cn/4 = 64 float4 per row
        int d4  = idx & 63;
        int l = l0 + row - 1;
        float4 v = make_float4(0.f, 0.f, 0.f, 0.f);
        if (l >= 0 && l < Ln)
            v = *(const float4*)&in[(b * Ln + l) * Cn + d4 * 4];
        *(float4*)&xs[row][d4 * 4] = v;
    }
    __syncthreads();

    const int f = t;
    float acc[RROWS];
    {
        float bz = bias[f];
        #pragma unroll
        for (int r = 0; r < RROWS; ++r) acc[r] = bz;
    }

    // d in chunks of 4 via ds_read_b128 (wave-uniform broadcast reads)
    for (int d = 0; d < Cn; d += 4) {
        float4 xr[RROWS + 2];
        #pragma unroll
        for (int j = 0; j < RROWS + 2; ++j)
            xr[j] = *(const float4*)&xs[j][d];
        #pragma unroll
        for (int k = 0; k < Kn; ++k) {
            const float* wp = &wT[(k * Cn + d) * Fn + f];
            float w0 = wp[0];
            float w1 = wp[Fn];
            float w2 = wp[2 * Fn];
            float w3 = wp[3 * Fn];
            #pragma unroll
            for (int r = 0; r < RROWS; ++r) {
                acc[r] += w0 * xr[r + k].x;
                acc[r] += w1 * xr[r + k].y;
                acc[r] += w2 * xr[r + k].z;
                acc[r] += w3 * xr[r + k].w;
            }
        }
    }

    #pragma unroll
    for (int r = 0; r < RROWS; ++r) hs[r][f] = acc[r];
    __syncthreads();

    // LayerNorm + ReLU: 4 waves, 4 rows each
    const int wave = t >> 6;
    const int lane = t & 63;
    for (int rr = 0; rr < 4; ++rr) {
        int r = wave * 4 + rr;
        float v0 = hs[r][lane];
        float v1 = hs[r][lane + 64];
        float v2 = hs[r][lane + 128];
        float v3 = hs[r][lane + 192];
        float s  = v0 + v1 + v2 + v3;
        float sq = v0 * v0 + v1 * v1 + v2 * v2 + v3 * v3;
        #pragma unroll
        for (int off = 32; off >= 1; off >>= 1) {
            s  += __shfl_xor(s,  off, 64);
            sq += __shfl_xor(sq, off, 64);
        }
        float mu  = s * (1.f / 256.f);
        float var = sq * (1.f / 256.f) - mu * mu;
        float rs  = rsqrtf(var + 1e-5f);
        int lbase = (b * Ln + l0 + r) * Fn;
        float vv[4] = {v0, v1, v2, v3};
        #pragma unroll
        for (int j = 0; j < 4; ++j) {
            int ff = lane + 64 * j;
            float o = (vv[j] - mu) * rs * gamma[ff] + beta[ff];
            out[lbase + ff] = fmaxf(o, 0.f);
        }
    }
}

// ---------- linear (F->1) + ReLU: one wave per (b,l) row ----------
__global__ __launch_bounds__(256) void linear_relu(
    const float* __restrict__ h,   // (B*L, F)
    const float* __restrict__ lw,  // (F)
    const float* __restrict__ lb,  // (1)
    float* __restrict__ dup)       // (B*L)
{
    int row  = blockIdx.x * 4 + (threadIdx.x >> 6);
    int lane = threadIdx.x & 63;
    const float* hp = h + row * Fn;
    float s = 0.f;
    #pragma unroll
    for (int j = 0; j < 4; ++j) {
        int ff = lane + 64 * j;
        s += hp[ff] * lw[ff];
    }
    #pragma unroll
    for (int off = 32; off >= 1; off >>= 1) s += __shfl_xor(s, off, 64);
    if (lane == 0) {
        dup[row] = fmaxf(s + lb[0], 0.f);
    }
}

// ---------- duration cumsum -> m->l map (one block per batch) ----------
__global__ __launch_bounds__(512) void scan_map(
    const int* __restrict__ target,  // (B,L) int32, values 1..3
    int* __restrict__ map)           // (B,M): l index, or -1 for zero-fill
{
    __shared__ int s[Ln];
    int b = blockIdx.x;
    int t = threadIdx.x;
    int v = target[b * Ln + t];
    s[t] = v;
    __syncthreads();
    for (int off = 1; off < Ln; off <<= 1) {
        int add = (t >= off) ? s[t - off] : 0;
        __syncthreads();
        s[t] += add;
        __syncthreads();
    }
    int cs    = s[t];        // inclusive cumsum
    int prev  = cs - v;      // exclusive
    int total = s[Ln - 1];
    for (int m = prev; m < cs; ++m) map[b * Mn + m] = t;
    for (int m = total + t; m < Mn; m += Ln) map[b * Mn + m] = -1;
}

// ---------- gather: out[b,m,:] = (map>=0) ? x[b,map,:] : 0  (float4) ----------
__global__ __launch_bounds__(256) void regulate(
    const float* __restrict__ x,   // (B,L,C)
    const int* __restrict__ map,   // (B,M)
    float* __restrict__ out)       // (B,M,C)
{
    int e4 = blockIdx.x * 256 + threadIdx.x;  // chunk of 4 floats
    int d4 = e4 & 63;         // 64 chunks per 256-wide row
    int bm = e4 >> 6;         // b*M + m
    int b  = bm >> 11;        // M = 2048
    int l  = map[bm];
    float4 val = make_float4(0.f, 0.f, 0.f, 0.f);
    if (l >= 0) {
        val = *((const float4*)(x + (size_t)(b * Ln + l) * Cn) + d4);
    }
    ((float4*)out)[e4] = val;
}

extern "C" void kernel_launch(void* const* d_in, const int* in_sizes, int n_in,
                              void* d_out, int out_size, void* d_ws, size_t ws_size,
                              hipStream_t stream) {
    const float* x    = (const float*)d_in[0];
    const int*   targ = (const int*)d_in[1];
    // d_in[2] = mel_max_length (scalar) = 2048, hardcoded
    const float* c1w = (const float*)d_in[3];
    const float* c1b = (const float*)d_in[4];
    const float* g1  = (const float*)d_in[5];
    const float* be1 = (const float*)d_in[6];
    const float* c2w = (const float*)d_in[7];
    const float* c2b = (const float*)d_in[8];
    const float* g2  = (const float*)d_in[9];
    const float* be2 = (const float*)d_in[10];
    const float* lw  = (const float*)d_in[11];
    const float* lb  = (const float*)d_in[12];

    float* out     = (float*)d_out;                       // (B,M,C)
    float* out_dup = out + (size_t)Bn * Mn * Cn;          // (B,L)

    // workspace layout (all f32)
    char* ws = (char*)d_ws;
    float* wT1 = (float*)ws;                                   // 786432 B
    float* wT2 = (float*)(ws + 786432);                        // 786432 B
    float* h1  = (float*)(ws + 2 * 786432);                    // 8 MiB
    float* h2  = (float*)(ws + 2 * 786432 + 8388608);          // 8 MiB
    int*   map = (int*)(ws + 2 * 786432 + 2 * 8388608);        // 128 KiB

    transpose_w<<<768, 256, 0, stream>>>(c1w, wT1);
    transpose_w<<<768, 256, 0, stream>>>(c2w, wT2);

    conv_ln_relu<<<Bn * (Ln / RROWS), 256, 0, stream>>>(x,  wT1, c1b, g1, be1, h1);
    conv_ln_relu<<<Bn * (Ln / RROWS), 256, 0, stream>>>(h1, wT2, c2b, g2, be2, h2);

    linear_relu<<<(Bn * Ln) / 4, 256, 0, stream>>>(h2, lw, lb, out_dup);

    scan_map<<<Bn, Ln, 0, stream>>>(targ, map);
    regulate<<<(Bn * Mn * Cn / 4) / 256, 256, 0, stream>>>(x, map, out);
}

// Round 3
// 149.377 us; speedup vs baseline: 1.6398x; 1.6398x over previous
//
#include <hip/hip_runtime.h>
#include <hip/hip_bf16.h>

// Problem constants (fixed by reference):
//   B=16, L=512, D=C=F=256, K=3, M=2048, EPS=1e-5
// Float tensors are f32; target int32. Convs run on bf16 MFMA (f32 accum).
#define Bn 16
#define Ln 512
#define Cn 256
#define Fn 256
#define Kn 3
#define Mn 2048

#define NKSTEP 24        // 768 / 32
#define MT 64            // L-rows per block
#define XS_PS 264        // LDS A-slab row stride (bf16 units); 528 B = 33*16
#define HS_PS 258        // LDS conv-result row stride (f32 units)

typedef __attribute__((ext_vector_type(8))) short short8;
typedef __attribute__((ext_vector_type(4))) float f32x4;

static __device__ __forceinline__ unsigned short f2bf(float f) {
    unsigned int u = __float_as_uint(f);
    unsigned int r = (u + 0x7fff + ((u >> 16) & 1)) >> 16;   // RNE
    return (unsigned short)r;
}

// ---------- pack both conv weights into per-lane MFMA B-fragment order ----------
// B[kappa][f] = w[f][d][k], kappa = k*256 + d.
// Fragment order: bp[((s*16 + nt)*64 + lane)*8 + j] = B[s*32 + (lane>>4)*8 + j][nt*16 + (lane&15)]
__global__ __launch_bounds__(256) void pack_w(const float* __restrict__ w1,
                                              const float* __restrict__ w2,
                                              unsigned short* __restrict__ bp1,
                                              unsigned short* __restrict__ bp2) {
    int idx = blockIdx.x * 256 + threadIdx.x;    // over 2 * 196608
    const float* w = w1;
    unsigned short* bp = bp1;
    int i = idx;
    if (i >= Fn * Cn * Kn) { i -= Fn * Cn * Kn; w = w2; bp = bp2; }
    int j    = i & 7;
    int lane = (i >> 3) & 63;
    int nt   = (i >> 9) & 15;
    int s    = i >> 13;
    int kap = s * 32 + ((lane >> 4) * 8) + j;
    int k = kap >> 8;
    int d = kap & 255;
    int f = nt * 16 + (lane & 15);
    bp[i] = f2bf(w[(f * Cn + d) * Kn + k]);
}

// ---------- fused conv1d(K=3,SAME) via MFMA + bias + LayerNorm + ReLU ----------
// One block = 64 L-rows of one batch, 4 waves; wave owns 4 m-tiles x 4 n-tiles.
// A-frag (16x16x32): A[m=lane&15][k=(lane>>4)*8+j]; C/D: col=lane&15, row=(lane>>4)*4+reg.
template <bool IS_F32_IN, bool DO_LINEAR>
__global__ __launch_bounds__(256) void conv_mfma(
    const void* __restrict__ in_,               // (B,L,C) f32 or bf16
    const unsigned short* __restrict__ bp,      // packed weights (bf16 frag order)
    const float* __restrict__ bias,             // (F)
    const float* __restrict__ gamma,            // (F)
    const float* __restrict__ beta,             // (F)
    const float* __restrict__ lw,               // (F)  [DO_LINEAR]
    const float* __restrict__ lb,               // (1)  [DO_LINEAR]
    unsigned short* __restrict__ hout,          // bf16 (B,L,F) [!DO_LINEAR]
    float* __restrict__ dup)                    // (B,L)        [DO_LINEAR]
{
    // union: A-slab (bf16, 66 x 264 = 34848 B) then conv result (f32, 64 x 258 = 66048 B)
    __shared__ __align__(16) char smem[64 * HS_PS * 4];
    unsigned short* xs = (unsigned short*)smem;
    float* hs = (float*)smem;

    const int t  = threadIdx.x;
    const int b  = blockIdx.x >> 3;          // 8 l-tiles per batch
    const int l0 = (blockIdx.x & 7) * MT;

    // ---- stage input rows [l0-1, l0+64], zero-padded, as bf16 ----
    if (IS_F32_IN) {
        const float* in = (const float*)in_;
        for (int idx = t; idx < 66 * 64; idx += 256) {     // 64 float4 per row
            int row = idx >> 6;
            int c4  = (idx & 63) * 4;
            int l = l0 + row - 1;
            float4 v = make_float4(0.f, 0.f, 0.f, 0.f);
            if (l >= 0 && l < Ln) v = *(const float4*)&in[((size_t)b * Ln + l) * Cn + c4];
            unsigned int lo = (unsigned int)f2bf(v.x) | ((unsigned int)f2bf(v.y) << 16);
            unsigned int hi = (unsigned int)f2bf(v.z) | ((unsigned int)f2bf(v.w) << 16);
            *(uint2*)&xs[row * XS_PS + c4] = make_uint2(lo, hi);
        }
    } else {
        const unsigned short* in = (const unsigned short*)in_;
        for (int idx = t; idx < 66 * 32; idx += 256) {     // 32 x (8 bf16) per row
            int row = idx >> 5;
            int c8  = (idx & 31) * 8;
            int l = l0 + row - 1;
            uint4 v = make_uint4(0u, 0u, 0u, 0u);
            if (l >= 0 && l < Ln) v = *(const uint4*)&in[((size_t)b * Ln + l) * Cn + c8];
            *(uint4*)&xs[row * XS_PS + c8] = v;
        }
    }
    __syncthreads();

    const int lane = t & 63;
    const int wv   = t >> 6;
    const int mrow = lane & 15;
    const int q    = lane >> 4;

    f32x4 acc[4][4] = {};

    for (int s = 0; s < NKSTEP; ++s) {
        int k    = s >> 3;
        int dcol = (s & 7) * 32 + q * 8;
        short8 bfr[4], afr[4];
        #pragma unroll
        for (int i = 0; i < 4; ++i)
            bfr[i] = *(const short8*)&bp[(size_t)((s * 16 + wv * 4 + i) * 64 + lane) * 8];
        #pragma unroll
        for (int mt = 0; mt < 4; ++mt)
            afr[mt] = *(const short8*)&xs[(mt * 16 + mrow + k) * XS_PS + dcol];
        #pragma unroll
        for (int mt = 0; mt < 4; ++mt)
            #pragma unroll
            for (int i = 0; i < 4; ++i)
                acc[mt][i] = __builtin_amdgcn_mfma_f32_16x16x32_bf16(
                    afr[mt], bfr[i], acc[mt][i], 0, 0, 0);
    }

    __syncthreads();   // done reading xs; smem becomes hs

    // scatter acc (+bias) into hs: l = mt*16 + q*4 + reg, f = (wv*4+i)*16 + mrow
    float biasr[4];
    #pragma unroll
    for (int i = 0; i < 4; ++i) biasr[i] = bias[(wv * 4 + i) * 16 + mrow];
    #pragma unroll
    for (int mt = 0; mt < 4; ++mt)
        #pragma unroll
        for (int i = 0; i < 4; ++i) {
            #pragma unroll
            for (int r = 0; r < 4; ++r) {
                int lrow = mt * 16 + q * 4 + r;
                hs[lrow * HS_PS + (wv * 4 + i) * 16 + mrow] = acc[mt][i][r] + biasr[i];
            }
        }
    __syncthreads();

    // ---- LayerNorm + ReLU (+ fused linear head): wave wv owns rows wv*16..+15 ----
    float g4[4], be4[4], lw4[4];
    #pragma unroll
    for (int j = 0; j < 4; ++j) {
        g4[j]  = gamma[lane + 64 * j];
        be4[j] = beta[lane + 64 * j];
        if (DO_LINEAR) lw4[j] = lw[lane + 64 * j];
    }
    float lb0 = DO_LINEAR ? lb[0] : 0.f;

    for (int rr = 0; rr < 16; ++rr) {
        int r = wv * 16 + rr;
        float v[4], s = 0.f, sq = 0.f;
        #pragma unroll
        for (int j = 0; j < 4; ++j) {
            v[j] = hs[r * HS_PS + lane + 64 * j];
            s  += v[j];
            sq += v[j] * v[j];
        }
        #pragma unroll
        for (int off = 32; off >= 1; off >>= 1) {
            s  += __shfl_xor(s,  off, 64);
            sq += __shfl_xor(sq, off, 64);
        }
        float mu  = s * (1.f / 256.f);
        float var = sq * (1.f / 256.f) - mu * mu;
        float rs  = rsqrtf(var + 1e-5f);
        int l = l0 + r;
        if (DO_LINEAR) {
            float dot = 0.f;
            #pragma unroll
            for (int j = 0; j < 4; ++j) {
                float o = fmaxf((v[j] - mu) * rs * g4[j] + be4[j], 0.f);
                dot += o * lw4[j];
            }
            #pragma unroll
            for (int off = 32; off >= 1; off >>= 1) dot += __shfl_xor(dot, off, 64);
            if (lane == 0) dup[b * Ln + l] = fmaxf(dot + lb0, 0.f);
        } else {
            #pragma unroll
            for (int j = 0; j < 4; ++j) {
                float o = fmaxf((v[j] - mu) * rs * g4[j] + be4[j], 0.f);
                hout[((size_t)b * Ln + l) * Fn + lane + 64 * j] = f2bf(o);
            }
        }
    }
}

// ---------- duration cumsum -> m->l map (one block per batch) ----------
__global__ __launch_bounds__(512) void scan_map(
    const int* __restrict__ target,  // (B,L) int32
    int* __restrict__ map)           // (B,M): l index, or -1 for zero-fill
{
    __shared__ int s[Ln];
    int b = blockIdx.x;
    int t = threadIdx.x;
    int v = target[b * Ln + t];
    s[t] = v;
    __syncthreads();
    for (int off = 1; off < Ln; off <<= 1) {
        int add = (t >= off) ? s[t - off] : 0;
        __syncthreads();
        s[t] += add;
        __syncthreads();
    }
    int cs    = s[t];
    int prev  = cs - v;
    int total = s[Ln - 1];
    for (int m = prev; m < cs; ++m) map[b * Mn + m] = t;
    for (int m = total + t; m < Mn; m += Ln) map[b * Mn + m] = -1;
}

// ---------- gather: out[b,m,:] = (map>=0) ? x[b,map,:] : 0  (float4) ----------
__global__ __launch_bounds__(256) void regulate(
    const float* __restrict__ x,   // (B,L,C)
    const int* __restrict__ map,   // (B,M)
    float* __restrict__ out)       // (B,M,C)
{
    int e4 = blockIdx.x * 256 + threadIdx.x;
    int d4 = e4 & 63;
    int bm = e4 >> 6;
    int b  = bm >> 11;
    int l  = map[bm];
    float4 val = make_float4(0.f, 0.f, 0.f, 0.f);
    if (l >= 0) {
        val = *((const float4*)(x + (size_t)(b * Ln + l) * Cn) + d4);
    }
    ((float4*)out)[e4] = val;
}

extern "C" void kernel_launch(void* const* d_in, const int* in_sizes, int n_in,
                              void* d_out, int out_size, void* d_ws, size_t ws_size,
                              hipStream_t stream) {
    const float* x    = (const float*)d_in[0];
    const int*   targ = (const int*)d_in[1];
    // d_in[2] = mel_max_length (scalar) = 2048, hardcoded
    const float* c1w = (const float*)d_in[3];
    const float* c1b = (const float*)d_in[4];
    const float* g1  = (const float*)d_in[5];
    const float* be1 = (const float*)d_in[6];
    const float* c2w = (const float*)d_in[7];
    const float* c2b = (const float*)d_in[8];
    const float* g2  = (const float*)d_in[9];
    const float* be2 = (const float*)d_in[10];
    const float* lw  = (const float*)d_in[11];
    const float* lb  = (const float*)d_in[12];

    float* out     = (float*)d_out;                       // (B,M,C)
    float* out_dup = out + (size_t)Bn * Mn * Cn;          // (B,L)

    // workspace layout
    char* ws = (char*)d_ws;
    unsigned short* bp1 = (unsigned short*)ws;                       // 384 KiB
    unsigned short* bp2 = (unsigned short*)(ws + 393216);            // 384 KiB
    unsigned short* h1  = (unsigned short*)(ws + 2 * 393216);        // 4 MiB bf16
    int*            map = (int*)(ws + 2 * 393216 + 4194304);         // 128 KiB

    pack_w<<<1536, 256, 0, stream>>>(c1w, c2w, bp1, bp2);

    conv_mfma<true,  false><<<Bn * 8, 256, 0, stream>>>(
        (const void*)x,  bp1, c1b, g1, be1, nullptr, nullptr, h1, nullptr);
    conv_mfma<false, true ><<<Bn * 8, 256, 0, stream>>>(
        (const void*)h1, bp2, c2b, g2, be2, lw, lb, nullptr, out_dup);

    scan_map<<<Bn, Ln, 0, stream>>>(targ, map);
    regulate<<<(Bn * Mn * Cn / 4) / 256, 256, 0, stream>>>(x, map, out);
}

// Round 4
// 117.819 us; speedup vs baseline: 2.0790x; 1.2679x over previous
//
#include <hip/hip_runtime.h>
#include <hip/hip_bf16.h>

// Problem constants (fixed by reference):
//   B=16, L=512, D=C=F=256, K=3, M=2048, EPS=1e-5
// Float tensors are f32; target int32. Convs run on bf16 MFMA (f32 accum).
#define Bn 16
#define Ln 512
#define Cn 256
#define Fn 256
#define Kn 3
#define Mn 2048

#define NKSTEP 24        // 768 / 32
#define MT 32            // L-rows per block -> grid 256 (1 block/CU)
#define XS_PS 264        // LDS A-slab row stride (bf16 units); 528 B = 33*16
#define NCONVBLK 256

typedef __attribute__((ext_vector_type(8))) short short8;
typedef __attribute__((ext_vector_type(4))) float f32x4;

static __device__ __forceinline__ unsigned short f2bf(float f) {
    unsigned int u = __float_as_uint(f);
    return (unsigned short)((u + 0x7fff + ((u >> 16) & 1)) >> 16);   // RNE
}

// ---------- K1: pack both conv weights into MFMA B-frag order + duration scan ----------
// blocks 0..1535: pack. bp[((s*16+nt)*64+lane)*8+j] = w[f=nt*16+(lane&15)][d][k],
//                 kappa = k*256+d = s*32 + (lane>>4)*8 + j.   (verified layout, r3)
// blocks 1536..1551: per-batch cumsum of target -> m->l map (-1 = zero-fill).
__global__ __launch_bounds__(256) void pack_scan(
    const float* __restrict__ w1, const float* __restrict__ w2,
    unsigned short* __restrict__ bp1, unsigned short* __restrict__ bp2,
    const int* __restrict__ target, int* __restrict__ map)
{
    __shared__ int ss[256];
    const int blk = blockIdx.x;
    const int t = threadIdx.x;
    if (blk < 1536) {
        int i = blk * 256 + t;
        const float* w = w1;
        unsigned short* bp = bp1;
        if (i >= Fn * Cn * Kn) { i -= Fn * Cn * Kn; w = w2; bp = bp2; }
        int j    = i & 7;
        int lane = (i >> 3) & 63;
        int nt   = (i >> 9) & 15;
        int s    = i >> 13;
        int kap = s * 32 + ((lane >> 4) * 8) + j;
        int k = kap >> 8;
        int d = kap & 255;
        int f = nt * 16 + (lane & 15);
        bp[i] = f2bf(w[(f * Cn + d) * Kn + k]);
    } else {
        int b = blk - 1536;
        int v0 = target[b * Ln + 2 * t];
        int v1 = target[b * Ln + 2 * t + 1];
        ss[t] = v0 + v1;
        __syncthreads();
        for (int off = 1; off < 256; off <<= 1) {
            int add = (t >= off) ? ss[t - off] : 0;
            __syncthreads();
            ss[t] += add;
            __syncthreads();
        }
        int S     = ss[t];        // inclusive pair-scan -> cumsum at 2t+1
        int total = ss[255];
        int cs1   = S;
        int cs0   = S - v1;
        int prev0 = cs0 - v0;
        for (int m = prev0; m < cs0; ++m) map[b * Mn + m] = 2 * t;
        for (int m = cs0;   m < cs1; ++m) map[b * Mn + m] = 2 * t + 1;
        for (int m = total + t; m < Mn; m += 256) map[b * Mn + m] = -1;
    }
}

// ---------- fused conv1d(K=3,SAME) via MFMA + bias + LayerNorm + ReLU ----------
// Conv blocks (0..255): 32 L-rows of one batch; 4 waves, wave = 2 m-tiles x 4 n-tiles.
// A-frag (16x16x32): A[m=lane&15][k=(lane>>4)*8+j]; C/D: col=lane&15, row=(lane>>4)*4+reg.
// LN is done in register space from the accumulator (no big LDS round-trip).
// WITH_REG: blocks >= 256 do the length-regulate gather instead (independent work).
template <bool IS_F32_IN, bool DO_LINEAR, bool WITH_REG>
__global__ __launch_bounds__(256) void conv_mfma(
    const void* __restrict__ in_,               // (B,L,C) f32 or bf16
    const unsigned short* __restrict__ bp,      // packed weights (bf16 frag order)
    const float* __restrict__ bias,             // (F)
    const float* __restrict__ gamma,            // (F)
    const float* __restrict__ beta,             // (F)
    const float* __restrict__ lw,               // (F)  [DO_LINEAR]
    const float* __restrict__ lb,               // (1)  [DO_LINEAR]
    unsigned short* __restrict__ hout,          // bf16 (B,L,F) [!DO_LINEAR]
    float* __restrict__ dup,                    // (B,L)        [DO_LINEAR]
    const float* __restrict__ gx,               // (B,L,C) f32  [WITH_REG]
    const int* __restrict__ gmap,               // (B,M)        [WITH_REG]
    float* __restrict__ gout)                   // (B,M,C)      [WITH_REG]
{
    __shared__ __align__(16) unsigned short xs[(MT + 2) * XS_PS];  // ~18 KB
    __shared__ float2 red[MT][4];                                  // 1 KB
    __shared__ float  red2[MT][4];                                 // 0.5 KB

    const int t = threadIdx.x;

    if (WITH_REG && blockIdx.x >= NCONVBLK) {
        // ---- length-regulate gather: out[b,m,:] = (map>=0) ? x[b,map,:] : 0 ----
        int e4 = (blockIdx.x - NCONVBLK) * 256 + t;   // float4 index
        int d4 = e4 & 63;
        int bm = e4 >> 6;
        int b  = bm >> 11;
        int l  = gmap[bm];
        float4 val = make_float4(0.f, 0.f, 0.f, 0.f);
        if (l >= 0) val = *((const float4*)(gx + (size_t)(b * Ln + l) * Cn) + d4);
        ((float4*)gout)[e4] = val;
        return;
    }

    const int b  = blockIdx.x >> 4;          // 16 l-tiles per batch
    const int l0 = (blockIdx.x & 15) * MT;

    // ---- stage input rows [l0-1, l0+32], zero-padded, as bf16 ----
    if (IS_F32_IN) {
        const float* in = (const float*)in_;
        for (int idx = t; idx < (MT + 2) * 64; idx += 256) {   // 64 float4 per row
            int row = idx >> 6;
            int c4  = (idx & 63) * 4;
            int l = l0 + row - 1;
            float4 v = make_float4(0.f, 0.f, 0.f, 0.f);
            if (l >= 0 && l < Ln) v = *(const float4*)&in[((size_t)b * Ln + l) * Cn + c4];
            unsigned int lo = (unsigned int)f2bf(v.x) | ((unsigned int)f2bf(v.y) << 16);
            unsigned int hi = (unsigned int)f2bf(v.z) | ((unsigned int)f2bf(v.w) << 16);
            *(uint2*)&xs[row * XS_PS + c4] = make_uint2(lo, hi);
        }
    } else {
        const unsigned short* in = (const unsigned short*)in_;
        for (int idx = t; idx < (MT + 2) * 32; idx += 256) {   // 32 x (8 bf16) per row
            int row = idx >> 5;
            int c8  = (idx & 31) * 8;
            int l = l0 + row - 1;
            uint4 v = make_uint4(0u, 0u, 0u, 0u);
            if (l >= 0 && l < Ln) v = *(const uint4*)&in[((size_t)b * Ln + l) * Cn + c8];
            *(uint4*)&xs[row * XS_PS + c8] = v;
        }
    }
    __syncthreads();

    const int lane = t & 63;
    const int wv   = t >> 6;      // n-group: cols wv*64 .. wv*64+63
    const int mrow = lane & 15;
    const int q    = lane >> 4;

    f32x4  acc[2][4] = {};
    short8 bfr[2][4];             // 2-slot ring, loaded 2 steps ahead
    short8 afr[2][2];

    auto loadB = [&](int s, int slot) {
        const unsigned short* p = bp + (size_t)((s * 16 + wv * 4) * 64 + lane) * 8;
        #pragma unroll
        for (int i = 0; i < 4; ++i)
            bfr[slot][i] = *(const short8*)(p + (size_t)i * 64 * 8);
    };
    auto loadA = [&](int s, int slot) {
        const int k    = s >> 3;
        const int dcol = (s & 7) * 32 + q * 8;
        #pragma unroll
        for (int mt = 0; mt < 2; ++mt)
            afr[slot][mt] = *(const short8*)&xs[(mt * 16 + mrow + k) * XS_PS + dcol];
    };

    loadB(0, 0); loadA(0, 0);
    loadB(1, 1); loadA(1, 1);

    #pragma unroll 2
    for (int s = 0; s < NKSTEP; ++s) {
        const int slot = s & 1;
        #pragma unroll
        for (int mt = 0; mt < 2; ++mt)
            #pragma unroll
            for (int i = 0; i < 4; ++i)
                acc[mt][i] = __builtin_amdgcn_mfma_f32_16x16x32_bf16(
                    afr[slot][mt], bfr[slot][i], acc[mt][i], 0, 0, 0);
        const int sn = (s + 2 < NKSTEP) ? (s + 2) : s;   // tail: harmless reload
        loadB(sn, slot);
        loadA(sn, slot);
    }

    // ---- epilogue: bias + LayerNorm from registers ----
    float gv[4], bv[4], lwv[4], biasv[4];
    #pragma unroll
    for (int i = 0; i < 4; ++i) {
        int col = wv * 64 + i * 16 + mrow;
        biasv[i] = bias[col];
        gv[i]    = gamma[col];
        bv[i]    = beta[col];
        if (DO_LINEAR) lwv[i] = lw[col];
    }
    #pragma unroll
    for (int mt = 0; mt < 2; ++mt)
        #pragma unroll
        for (int i = 0; i < 4; ++i)
            #pragma unroll
            for (int r = 0; r < 4; ++r)
                acc[mt][i][r] += biasv[i];

    // per-row partial sums over this wave's 64 cols: in-lane over i, shuffle over mrow lanes
    #pragma unroll
    for (int mt = 0; mt < 2; ++mt)
        #pragma unroll
        for (int r = 0; r < 4; ++r) {
            float s  = acc[mt][0][r] + acc[mt][1][r] + acc[mt][2][r] + acc[mt][3][r];
            float sq = acc[mt][0][r] * acc[mt][0][r] + acc[mt][1][r] * acc[mt][1][r]
                     + acc[mt][2][r] * acc[mt][2][r] + acc[mt][3][r] * acc[mt][3][r];
            #pragma unroll
            for (int off = 1; off <= 8; off <<= 1) {
                s  += __shfl_xor(s,  off, 64);
                sq += __shfl_xor(sq, off, 64);
            }
            if (mrow == 0) red[mt * 16 + q * 4 + r][wv] = make_float2(s, sq);
        }
    __syncthreads();

    float muv[2][4], rsv[2][4];
    #pragma unroll
    for (int mt = 0; mt < 2; ++mt)
        #pragma unroll
        for (int r = 0; r < 4; ++r) {
            int row = mt * 16 + q * 4 + r;
            float2 p0 = red[row][0], p1 = red[row][1], p2 = red[row][2], p3 = red[row][3];
            float s  = p0.x + p1.x + p2.x + p3.x;
            float sq = p0.y + p1.y + p2.y + p3.y;
            float mu  = s * (1.f / 256.f);
            float var = sq * (1.f / 256.f) - mu * mu;
            muv[mt][r] = mu;
            rsv[mt][r] = rsqrtf(var + 1e-5f);
        }

    if (!DO_LINEAR) {
        // store relu(LN(h)) as bf16
        #pragma unroll
        for (int mt = 0; mt < 2; ++mt)
            #pragma unroll
            for (int r = 0; r < 4; ++r) {
                int l = l0 + mt * 16 + q * 4 + r;
                size_t base = ((size_t)b * Ln + l) * Fn;
                #pragma unroll
                for (int i = 0; i < 4; ++i) {
                    float o = fmaxf((acc[mt][i][r] - muv[mt][r]) * rsv[mt][r] * gv[i] + bv[i], 0.f);
                    hout[base + wv * 64 + i * 16 + mrow] = f2bf(o);
                }
            }
    } else {
        // fused linear head: dup = relu( relu(LN(h)) . lw + lb )
        #pragma unroll
        for (int mt = 0; mt < 2; ++mt)
            #pragma unroll
            for (int r = 0; r < 4; ++r) {
                float dot = 0.f;
                #pragma unroll
                for (int i = 0; i < 4; ++i) {
                    float o = fmaxf((acc[mt][i][r] - muv[mt][r]) * rsv[mt][r] * gv[i] + bv[i], 0.f);
                    dot += o * lwv[i];
                }
                #pragma unroll
                for (int off = 1; off <= 8; off <<= 1)
                    dot += __shfl_xor(dot, off, 64);
                if (mrow == 0) red2[mt * 16 + q * 4 + r][wv] = dot;
            }
        __syncthreads();
        if (t < MT) {
            float d = red2[t][0] + red2[t][1] + red2[t][2] + red2[t][3];
            dup[b * Ln + l0 + t] = fmaxf(d + lb[0], 0.f);
        }
    }
}

extern "C" void kernel_launch(void* const* d_in, const int* in_sizes, int n_in,
                              void* d_out, int out_size, void* d_ws, size_t ws_size,
                              hipStream_t stream) {
    const float* x    = (const float*)d_in[0];
    const int*   targ = (const int*)d_in[1];
    // d_in[2] = mel_max_length (scalar) = 2048, hardcoded
    const float* c1w = (const float*)d_in[3];
    const float* c1b = (const float*)d_in[4];
    const float* g1  = (const float*)d_in[5];
    const float* be1 = (const float*)d_in[6];
    const float* c2w = (const float*)d_in[7];
    const float* c2b = (const float*)d_in[8];
    const float* g2  = (const float*)d_in[9];
    const float* be2 = (const float*)d_in[10];
    const float* lw  = (const float*)d_in[11];
    const float* lb  = (const float*)d_in[12];

    float* out     = (float*)d_out;                       // (B,M,C)
    float* out_dup = out + (size_t)Bn * Mn * Cn;          // (B,L)

    // workspace layout
    char* ws = (char*)d_ws;
    unsigned short* bp1 = (unsigned short*)ws;                       // 384 KiB
    unsigned short* bp2 = (unsigned short*)(ws + 393216);            // 384 KiB
    unsigned short* h1  = (unsigned short*)(ws + 2 * 393216);        // 4 MiB bf16
    int*            map = (int*)(ws + 2 * 393216 + 4194304);         // 128 KiB

    // K1: weight pack (1536 blocks) + duration scan (16 blocks)
    pack_scan<<<1552, 256, 0, stream>>>(c1w, c2w, bp1, bp2, targ, map);

    // K2: conv1 (blocks 0..255) + length-regulate gather (blocks 256..8447)
    conv_mfma<true, false, true><<<NCONVBLK + (Bn * Mn * Cn / 4) / 256, 256, 0, stream>>>(
        (const void*)x, bp1, c1b, g1, be1, nullptr, nullptr, h1, nullptr,
        x, map, out);

    // K3: conv2 + fused linear head -> dup
    conv_mfma<false, true, false><<<NCONVBLK, 256, 0, stream>>>(
        (const void*)h1, bp2, c2b, g2, be2, lw, lb, nullptr, out_dup,
        nullptr, nullptr, nullptr);
}